// Round 1
// baseline (784.234 us; speedup 1.0000x reference)
//
#include <hip/hip_runtime.h>
#include <hip/hip_bf16.h>
#include <math.h>

#define NEXP 16
#define CAP  512
#define TTOK 1024
#define HDIM 2048
#define IDIM 1408

typedef float fx4 __attribute__((ext_vector_type(4)));
typedef short short8 __attribute__((ext_vector_type(8)));
typedef unsigned int u32;
typedef unsigned long long u64;

__device__ __forceinline__ unsigned short f2bf(float f) {
    u32 u = __float_as_uint(f);
    u += 0x7FFFu + ((u >> 16) & 1u);       // round-to-nearest-even
    return (unsigned short)(u >> 16);
}
__device__ __forceinline__ float bf2f(unsigned short h) {
    return __uint_as_float(((u32)h) << 16);
}

// ---------------- router: top-2 of softmax == top-2 of logits; weights = 2-way softmax
__global__ void router_kernel(const float* __restrict__ logits,
                              int* __restrict__ topi, float* __restrict__ topw,
                              int* __restrict__ cnt1) {
    int t = blockIdx.x * blockDim.x + threadIdx.x;
    if (t >= TTOK) return;
    const float* l = logits + t * NEXP;
    float b0 = -INFINITY, b1 = -INFINITY; int i0 = 0, i1 = 0;
    for (int e = 0; e < NEXP; ++e) {
        float v = l[e];
        if (v > b0) { b1 = b0; i1 = i0; b0 = v; i0 = e; }
        else if (v > b1) { b1 = v; i1 = e; }
    }
    float w0 = 1.f / (1.f + expf(b1 - b0));
    topi[t*2]   = i0; topi[t*2+1] = i1;
    topw[t*2]   = w0; topw[t*2+1] = 1.f - w0;
    atomicAdd(&cnt1[i0], 1);
    atomicAdd(&cnt1[i1], 1);
}

__global__ void scan_kernel(const int* __restrict__ cnt1, int* __restrict__ base) {
    if (threadIdx.x == 0 && blockIdx.x == 0) {
        int s = 0;
        for (int e = 0; e < NEXP; ++e) {
            base[e] = s;
            int c = cnt1[e]; if (c > CAP) c = CAP;
            s += c;
        }
        base[NEXP] = s;
    }
}

// slot assignment by atomics: with no capacity overflow (true for this input),
// any within-expert permutation yields identical output (slot mapping is a bijection)
__global__ void assign_kernel(const int* __restrict__ topi, const int* __restrict__ base,
                              int* __restrict__ cnt2,
                              int* __restrict__ slot_token, int* __restrict__ slot_of) {
    int t = blockIdx.x * blockDim.x + threadIdx.x;
    if (t >= TTOK) return;
    for (int k = 0; k < 2; ++k) {
        int e = topi[t*2+k];
        int p = atomicAdd(&cnt2[e], 1);
        if (p < CAP) {
            int s = base[e] + p;
            slot_token[s] = t;
            slot_of[t*2+k] = s;
        } else {
            slot_of[t*2+k] = -1;
        }
    }
}

// ---------------- GEMM: C[rows x NDIM] = A(bf16) @ W[e]^T, per expert, compact rows
// A: gathered x rows (fp32, GATHER) or act rows (bf16). W fp32, converted to bf16.
// 128x128 block tile, BK=32, 4 waves in 2x2, each wave 64x64 via 4x4 of 16x16x32 MFMA.
#define LDA 40   // 32 + 8 bf16 pad: 16B-aligned quad reads, <=2-way bank conflicts

template<int NDIM, int KDIM, bool GATHER>
__global__ __launch_bounds__(256) void gemm_bt_kernel(
    const float* __restrict__ Af32,
    const unsigned short* __restrict__ Abf16,
    const float* __restrict__ W,
    unsigned short* __restrict__ Cout,
    const int* __restrict__ slot_token,
    const int* __restrict__ base)
{
    const int e = blockIdx.z;
    const int n0 = base[e];
    const int rows = base[e+1] - n0;
    const int rtile = blockIdx.y * 128;
    if (rtile >= rows) return;
    const int col0 = blockIdx.x * 128;

    __shared__ unsigned short sA[128 * LDA];
    __shared__ unsigned short sB[128 * LDA];

    const int tid = threadIdx.x;
    const int lane = tid & 63;
    const int wv = tid >> 6;
    const int wm = wv >> 1, wn = wv & 1;
    const int lr = lane & 15;
    const int quad = lane >> 4;

    fx4 acc[4][4];
    #pragma unroll
    for (int i = 0; i < 4; ++i)
        #pragma unroll
        for (int j = 0; j < 4; ++j) acc[i][j] = (fx4)0.f;

    // A-row source ids, constant across K loop
    int tok[4];
    if (GATHER) {
        int rr = tid >> 3;
        #pragma unroll
        for (int p = 0; p < 4; ++p) {
            int grow = rtile + rr + p*32;
            tok[p] = (grow < rows) ? slot_token[n0 + grow] : -1;
        }
    } else {
        int rr = tid >> 2;
        #pragma unroll
        for (int p = 0; p < 2; ++p) {
            int grow = rtile + rr + p*64;
            tok[p] = (grow < rows) ? (n0 + grow) : -1;
        }
    }

    const float* Wp = W + ((size_t)e * NDIM + col0) * KDIM;

    const int KT = KDIM / 32;
    for (int kt = 0; kt < KT; ++kt) {
        const int k0 = kt * 32;
        __syncthreads();
        // ---- stage A
        if (GATHER) {
            int g = tid & 7, rr = tid >> 3;
            #pragma unroll
            for (int p = 0; p < 4; ++p) {
                int row = rr + p*32;
                u64 v = 0;
                if (tok[p] >= 0) {
                    fx4 f = *(const fx4*)(Af32 + (size_t)tok[p]*KDIM + k0 + g*4);
                    u32 lo = (u32)f2bf(f.x) | ((u32)f2bf(f.y) << 16);
                    u32 hi = (u32)f2bf(f.z) | ((u32)f2bf(f.w) << 16);
                    v = (u64)lo | ((u64)hi << 32);
                }
                *(u64*)&sA[row*LDA + g*4] = v;
            }
        } else {
            int g = tid & 3, rr = tid >> 2;
            #pragma unroll
            for (int p = 0; p < 2; ++p) {
                int row = rr + p*64;
                fx4 v = (fx4)0.f;
                if (tok[p] >= 0)
                    v = *(const fx4*)(Abf16 + (size_t)tok[p]*KDIM + k0 + g*8);
                *(fx4*)&sA[row*LDA + g*8] = v;
            }
        }
        // ---- stage B (always full tile; NDIM % 128 == 0)
        {
            int g = tid & 7, rr = tid >> 3;
            #pragma unroll
            for (int p = 0; p < 4; ++p) {
                int row = rr + p*32;
                fx4 f = *(const fx4*)(Wp + (size_t)row*KDIM + k0 + g*4);
                u32 lo = (u32)f2bf(f.x) | ((u32)f2bf(f.y) << 16);
                u32 hi = (u32)f2bf(f.z) | ((u32)f2bf(f.w) << 16);
                *(u64*)&sB[row*LDA + g*4] = (u64)lo | ((u64)hi << 32);
            }
        }
        __syncthreads();
        // ---- fragments + MFMA
        short8 af[4], bfr[4];
        #pragma unroll
        for (int mi = 0; mi < 4; ++mi) {
            int row = wm*64 + mi*16 + lr;
            af[mi] = *(const short8*)&sA[row*LDA + quad*8];
        }
        #pragma unroll
        for (int ni = 0; ni < 4; ++ni) {
            int row = wn*64 + ni*16 + lr;
            bfr[ni] = *(const short8*)&sB[row*LDA + quad*8];
        }
        #pragma unroll
        for (int mi = 0; mi < 4; ++mi)
            #pragma unroll
            for (int ni = 0; ni < 4; ++ni)
                acc[mi][ni] = __builtin_amdgcn_mfma_f32_16x16x32_bf16(
                    af[mi], bfr[ni], acc[mi][ni], 0, 0, 0);
    }

    // ---- epilogue: C/D layout col=lane&15, row=quad*4+reg
    #pragma unroll
    for (int mi = 0; mi < 4; ++mi) {
        #pragma unroll
        for (int r = 0; r < 4; ++r) {
            int grow = rtile + wm*64 + mi*16 + quad*4 + r;
            if (grow < rows) {
                size_t orow = (size_t)(n0 + grow) * NDIM;
                #pragma unroll
                for (int ni = 0; ni < 4; ++ni) {
                    int gcol = col0 + wn*64 + ni*16 + lr;
                    Cout[orow + gcol] = f2bf(acc[mi][ni][r]);
                }
            }
        }
    }
}

// ---------------- silu(gate)*up, bf16 in/out, vec8
__global__ void silu_kernel(const unsigned short* __restrict__ h,
                            unsigned short* __restrict__ act,
                            const int* __restrict__ base) {
    const int R = base[NEXP];
    int idx = blockIdx.x * blockDim.x + threadIdx.x;   // over R*(IDIM/8)
    int row = idx / (IDIM/8);
    int j   = idx % (IDIM/8);
    if (row >= R) return;
    const unsigned short* g = h + (size_t)row * (2*IDIM) + j*8;
    const unsigned short* u = g + IDIM;
    unsigned short go[8], uo[8], ao[8];
    *(fx4*)go = *(const fx4*)g;
    *(fx4*)uo = *(const fx4*)u;
    #pragma unroll
    for (int i = 0; i < 8; ++i) {
        float gv = bf2f(go[i]), uv = bf2f(uo[i]);
        float s = gv / (1.f + __expf(-gv));
        ao[i] = f2bf(s * uv);
    }
    *(fx4*)&act[(size_t)row*IDIM + j*8] = *(fx4*)ao;
}

// ---------------- combine: out[t] = w0*y[s0] + w1*y[s1]
__global__ void combine_kernel(const unsigned short* __restrict__ ybuf,
                               const int* __restrict__ slot_of,
                               const float* __restrict__ topw,
                               float* __restrict__ out) {
    int t = blockIdx.x;
    int c = threadIdx.x * 8;          // 256 threads x 8 = 2048
    int s0 = slot_of[t*2], s1 = slot_of[t*2+1];
    float w0 = topw[t*2], w1 = topw[t*2+1];
    float res[8];
    #pragma unroll
    for (int i = 0; i < 8; ++i) res[i] = 0.f;
    if (s0 >= 0) {
        unsigned short y[8];
        *(fx4*)y = *(const fx4*)(ybuf + (size_t)s0*HDIM + c);
        #pragma unroll
        for (int i = 0; i < 8; ++i) res[i] += w0 * bf2f(y[i]);
    }
    if (s1 >= 0) {
        unsigned short y[8];
        *(fx4*)y = *(const fx4*)(ybuf + (size_t)s1*HDIM + c);
        #pragma unroll
        for (int i = 0; i < 8; ++i) res[i] += w1 * bf2f(y[i]);
    }
    float* o = out + (size_t)t*HDIM + c;
    *(fx4*)o       = *(fx4*)res;
    *(fx4*)(o + 4) = *(fx4*)(res + 4);
}

extern "C" void kernel_launch(void* const* d_in, const int* in_sizes, int n_in,
                              void* d_out, int out_size, void* d_ws, size_t ws_size,
                              hipStream_t stream) {
    const float* x      = (const float*)d_in[0];
    const float* logits = (const float*)d_in[1];
    const float* w13    = (const float*)d_in[2];
    const float* w2     = (const float*)d_in[3];
    float* out = (float*)d_out;

    char* ws = (char*)d_ws;
    size_t off = 0;
    auto alloc = [&](size_t bytes) -> void* {
        void* p = ws + off;
        off += (bytes + 255) & ~(size_t)255;
        return p;
    };
    int*   topi       = (int*)  alloc(TTOK*2*sizeof(int));
    float* topw       = (float*)alloc(TTOK*2*sizeof(float));
    int*   cnt1       = (int*)  alloc(NEXP*sizeof(int));
    int*   cnt2       = (int*)  alloc(NEXP*sizeof(int));
    int*   base       = (int*)  alloc((NEXP+1)*sizeof(int));
    int*   slot_token = (int*)  alloc(TTOK*2*sizeof(int));
    int*   slot_of    = (int*)  alloc(TTOK*2*sizeof(int));
    unsigned short* h    = (unsigned short*)alloc((size_t)TTOK*2 * (2*IDIM) * 2);
    unsigned short* act  = (unsigned short*)alloc((size_t)TTOK*2 * IDIM * 2);
    unsigned short* ybuf = (unsigned short*)alloc((size_t)TTOK*2 * HDIM * 2);

    hipMemsetAsync(cnt1, 0, NEXP*sizeof(int), stream);
    hipMemsetAsync(cnt2, 0, NEXP*sizeof(int), stream);

    router_kernel<<<dim3((TTOK+255)/256), 256, 0, stream>>>(logits, topi, topw, cnt1);
    scan_kernel<<<1, 64, 0, stream>>>(cnt1, base);
    assign_kernel<<<dim3((TTOK+255)/256), 256, 0, stream>>>(topi, base, cnt2, slot_token, slot_of);

    // GEMM1: h = x_gather @ w13^T   (NDIM=2816, KDIM=2048)
    gemm_bt_kernel<2*IDIM, HDIM, true>
        <<<dim3(2*IDIM/128, CAP/128, NEXP), 256, 0, stream>>>(
            x, nullptr, w13, h, slot_token, base);

    silu_kernel<<<dim3((TTOK*2*(IDIM/8) + 255)/256), 256, 0, stream>>>(h, act, base);

    // GEMM2: y = act @ w2^T         (NDIM=2048, KDIM=1408)
    gemm_bt_kernel<HDIM, IDIM, false>
        <<<dim3(HDIM/128, CAP/128, NEXP), 256, 0, stream>>>(
            nullptr, act, w2, ybuf, slot_token, base);

    combine_kernel<<<dim3(TTOK), 256, 0, stream>>>(ybuf, slot_of, topw, out);
}

// Round 2
// 758.523 us; speedup vs baseline: 1.0339x; 1.0339x over previous
//
#include <hip/hip_runtime.h>
#include <hip/hip_bf16.h>
#include <math.h>

#define NEXP 16
#define CAP  512
#define TTOK 1024
#define HDIM 2048
#define IDIM 1408

typedef float fx4 __attribute__((ext_vector_type(4)));
typedef short short8 __attribute__((ext_vector_type(8)));
typedef unsigned int u32;
typedef unsigned long long u64;

__device__ __forceinline__ unsigned short f2bf(float f) {
    u32 u = __float_as_uint(f);
    u += 0x7FFFu + ((u >> 16) & 1u);       // round-to-nearest-even
    return (unsigned short)(u >> 16);
}
__device__ __forceinline__ float bf2f(unsigned short h) {
    return __uint_as_float(((u32)h) << 16);
}
__device__ __forceinline__ u64 pack4bf(fx4 f) {
    u32 lo = (u32)f2bf(f.x) | ((u32)f2bf(f.y) << 16);
    u32 hi = (u32)f2bf(f.z) | ((u32)f2bf(f.w) << 16);
    return (u64)lo | ((u64)hi << 32);
}

// ---------------- router: top-2 of softmax == top-2 of logits; weights = 2-way softmax
__global__ void router_kernel(const float* __restrict__ logits,
                              int* __restrict__ topi, float* __restrict__ topw,
                              int* __restrict__ cnt1) {
    int t = blockIdx.x * blockDim.x + threadIdx.x;
    if (t >= TTOK) return;
    const float* l = logits + t * NEXP;
    float b0 = -INFINITY, b1 = -INFINITY; int i0 = 0, i1 = 0;
    for (int e = 0; e < NEXP; ++e) {
        float v = l[e];
        if (v > b0) { b1 = b0; i1 = i0; b0 = v; i0 = e; }
        else if (v > b1) { b1 = v; i1 = e; }
    }
    float w0 = 1.f / (1.f + expf(b1 - b0));
    topi[t*2]   = i0; topi[t*2+1] = i1;
    topw[t*2]   = w0; topw[t*2+1] = 1.f - w0;
    atomicAdd(&cnt1[i0], 1);
    atomicAdd(&cnt1[i1], 1);
}

__global__ void scan_kernel(const int* __restrict__ cnt1, int* __restrict__ base) {
    if (threadIdx.x == 0 && blockIdx.x == 0) {
        int s = 0;
        for (int e = 0; e < NEXP; ++e) {
            base[e] = s;
            int c = cnt1[e]; if (c > CAP) c = CAP;
            s += c;
        }
        base[NEXP] = s;
    }
}

__global__ void assign_kernel(const int* __restrict__ topi, const int* __restrict__ base,
                              int* __restrict__ cnt2,
                              int* __restrict__ slot_token, int* __restrict__ slot_of) {
    int t = blockIdx.x * blockDim.x + threadIdx.x;
    if (t >= TTOK) return;
    for (int k = 0; k < 2; ++k) {
        int e = topi[t*2+k];
        int p = atomicAdd(&cnt2[e], 1);
        if (p < CAP) {
            int s = base[e] + p;
            slot_token[s] = t;
            slot_of[t*2+k] = s;
        } else {
            slot_of[t*2+k] = -1;
        }
    }
}

// ---------------- GEMM: C[rows x NDIM] = A(bf16) @ W[e]^T, per expert, compact rows
// 128(rows) x 64(cols) block tile, BK=32, 4 waves stacked along rows (32 rows each).
// Software pipeline: register prefetch of tile k+1 overlaps MFMA on tile k;
// LDS double-buffered so there is only ONE barrier per K iteration and the
// global loads stay in flight across the entire compute phase.
#define LDA 40   // row stride in shorts: 80 B, 16B-aligned, <=2-way bank aliasing

template<int NDIM, int KDIM, bool GATHER>
__global__ __launch_bounds__(256) void gemm_bt_kernel(
    const float* __restrict__ Af32,
    const unsigned short* __restrict__ Abf16,
    const float* __restrict__ W,
    unsigned short* __restrict__ Cout,
    const int* __restrict__ slot_token,
    const int* __restrict__ base)
{
    const int e = blockIdx.z;
    const int n0 = base[e];
    const int rows = base[e+1] - n0;
    const int rtile = blockIdx.y * 128;
    if (rtile >= rows) return;
    const int col0 = blockIdx.x * 64;

    __shared__ unsigned short sA[2][128 * LDA];
    __shared__ unsigned short sB[2][64 * LDA];

    const int tid = threadIdx.x;
    const int lane = tid & 63;
    const int wv = tid >> 6;          // wave 0..3 -> rows [32w, 32w+32)
    const int lr = lane & 15;
    const int quad = lane >> 4;

    fx4 acc[2][4];
    #pragma unroll
    for (int i = 0; i < 2; ++i)
        #pragma unroll
        for (int j = 0; j < 4; ++j) acc[i][j] = (fx4)0.f;

    // ---- staging thread maps
    const int bg = tid & 7, bc = tid >> 3;         // B: k-seg(4 fp32), col (0..31)
    const int ag = tid & 7, ar = tid >> 3;         // A fp32 gather: 4 rows
    const int ag2 = tid & 3, ar2 = tid >> 2;       // A bf16: 2 rows

    int tok[4];
    if (GATHER) {
        #pragma unroll
        for (int p = 0; p < 4; ++p) {
            int grow = rtile + ar + p*32;
            tok[p] = (grow < rows) ? slot_token[n0 + grow] : -1;
        }
    } else {
        #pragma unroll
        for (int p = 0; p < 2; ++p) {
            int grow = rtile + ar2 + p*64;
            tok[p] = (grow < rows) ? (n0 + grow) : -1;
        }
    }

    const float* Wp = W + ((size_t)e * NDIM + col0) * KDIM;

    fx4 pa[4], pb[2];

    auto prefetch = [&](int k0) {
        #pragma unroll
        for (int p = 0; p < 2; ++p)
            pb[p] = *(const fx4*)(Wp + (size_t)(bc + p*32) * KDIM + k0 + bg*4);
        if (GATHER) {
            #pragma unroll
            for (int p = 0; p < 4; ++p)
                pa[p] = (tok[p] >= 0)
                    ? *(const fx4*)(Af32 + (size_t)tok[p]*KDIM + k0 + ag*4)
                    : (fx4)0.f;
        } else {
            #pragma unroll
            for (int p = 0; p < 2; ++p)
                pa[p] = (tok[p] >= 0)
                    ? *(const fx4*)(Abf16 + (size_t)tok[p]*KDIM + k0 + ag2*8)
                    : (fx4)0.f;
        }
    };
    auto stage = [&](int buf) {
        #pragma unroll
        for (int p = 0; p < 2; ++p)
            *(u64*)&sB[buf][(bc + p*32)*LDA + bg*4] = pack4bf(pb[p]);
        if (GATHER) {
            #pragma unroll
            for (int p = 0; p < 4; ++p)
                *(u64*)&sA[buf][(ar + p*32)*LDA + ag*4] = pack4bf(pa[p]);
        } else {
            #pragma unroll
            for (int p = 0; p < 2; ++p)
                *(fx4*)&sA[buf][(ar2 + p*64)*LDA + ag2*8] = pa[p];
        }
    };

    prefetch(0);
    stage(0);
    __syncthreads();

    const int KT = KDIM / 32;
    for (int kt = 0; kt < KT; ++kt) {
        const int cur = kt & 1;
        if (kt + 1 < KT) prefetch((kt + 1) * 32);   // loads in flight during MFMA

        short8 af[2], bfr[4];
        #pragma unroll
        for (int mi = 0; mi < 2; ++mi)
            af[mi] = *(const short8*)&sA[cur][(wv*32 + mi*16 + lr)*LDA + quad*8];
        #pragma unroll
        for (int ni = 0; ni < 4; ++ni)
            bfr[ni] = *(const short8*)&sB[cur][(ni*16 + lr)*LDA + quad*8];
        #pragma unroll
        for (int mi = 0; mi < 2; ++mi)
            #pragma unroll
            for (int ni = 0; ni < 4; ++ni)
                acc[mi][ni] = __builtin_amdgcn_mfma_f32_16x16x32_bf16(
                    af[mi], bfr[ni], acc[mi][ni], 0, 0, 0);

        if (kt + 1 < KT) {
            stage(1 - cur);        // waits the prefetch loads here (post-MFMA)
            __syncthreads();       // single barrier per iteration
        }
    }

    // ---- epilogue: C/D layout col=lane&15, row=quad*4+reg
    #pragma unroll
    for (int mi = 0; mi < 2; ++mi) {
        #pragma unroll
        for (int r = 0; r < 4; ++r) {
            int grow = rtile + wv*32 + mi*16 + quad*4 + r;
            if (grow < rows) {
                size_t orow = (size_t)(n0 + grow) * NDIM;
                #pragma unroll
                for (int ni = 0; ni < 4; ++ni) {
                    int gcol = col0 + ni*16 + lr;
                    Cout[orow + gcol] = f2bf(acc[mi][ni][r]);
                }
            }
        }
    }
}

// ---------------- silu(gate)*up, bf16 in/out, vec8
__global__ void silu_kernel(const unsigned short* __restrict__ h,
                            unsigned short* __restrict__ act,
                            const int* __restrict__ base) {
    const int R = base[NEXP];
    int idx = blockIdx.x * blockDim.x + threadIdx.x;
    int row = idx / (IDIM/8);
    int j   = idx % (IDIM/8);
    if (row >= R) return;
    const unsigned short* g = h + (size_t)row * (2*IDIM) + j*8;
    const unsigned short* u = g + IDIM;
    unsigned short go[8], uo[8], ao[8];
    *(fx4*)go = *(const fx4*)g;
    *(fx4*)uo = *(const fx4*)u;
    #pragma unroll
    for (int i = 0; i < 8; ++i) {
        float gv = bf2f(go[i]), uv = bf2f(uo[i]);
        float s = gv / (1.f + __expf(-gv));
        ao[i] = f2bf(s * uv);
    }
    *(fx4*)&act[(size_t)row*IDIM + j*8] = *(fx4*)ao;
}

// ---------------- combine: out[t] = w0*y[s0] + w1*y[s1]
__global__ void combine_kernel(const unsigned short* __restrict__ ybuf,
                               const int* __restrict__ slot_of,
                               const float* __restrict__ topw,
                               float* __restrict__ out) {
    int t = blockIdx.x;
    int c = threadIdx.x * 8;
    int s0 = slot_of[t*2], s1 = slot_of[t*2+1];
    float w0 = topw[t*2], w1 = topw[t*2+1];
    float res[8];
    #pragma unroll
    for (int i = 0; i < 8; ++i) res[i] = 0.f;
    if (s0 >= 0) {
        unsigned short y[8];
        *(fx4*)y = *(const fx4*)(ybuf + (size_t)s0*HDIM + c);
        #pragma unroll
        for (int i = 0; i < 8; ++i) res[i] += w0 * bf2f(y[i]);
    }
    if (s1 >= 0) {
        unsigned short y[8];
        *(fx4*)y = *(const fx4*)(ybuf + (size_t)s1*HDIM + c);
        #pragma unroll
        for (int i = 0; i < 8; ++i) res[i] += w1 * bf2f(y[i]);
    }
    float* o = out + (size_t)t*HDIM + c;
    *(fx4*)o       = *(fx4*)res;
    *(fx4*)(o + 4) = *(fx4*)(res + 4);
}

extern "C" void kernel_launch(void* const* d_in, const int* in_sizes, int n_in,
                              void* d_out, int out_size, void* d_ws, size_t ws_size,
                              hipStream_t stream) {
    const float* x      = (const float*)d_in[0];
    const float* logits = (const float*)d_in[1];
    const float* w13    = (const float*)d_in[2];
    const float* w2     = (const float*)d_in[3];
    float* out = (float*)d_out;

    char* ws = (char*)d_ws;
    size_t off = 0;
    auto alloc = [&](size_t bytes) -> void* {
        void* p = ws + off;
        off += (bytes + 255) & ~(size_t)255;
        return p;
    };
    int*   topi       = (int*)  alloc(TTOK*2*sizeof(int));
    float* topw       = (float*)alloc(TTOK*2*sizeof(float));
    int*   cnt1       = (int*)  alloc(NEXP*sizeof(int));
    int*   cnt2       = (int*)  alloc(NEXP*sizeof(int));
    int*   base       = (int*)  alloc((NEXP+1)*sizeof(int));
    int*   slot_token = (int*)  alloc(TTOK*2*sizeof(int));
    int*   slot_of    = (int*)  alloc(TTOK*2*sizeof(int));
    unsigned short* h    = (unsigned short*)alloc((size_t)TTOK*2 * (2*IDIM) * 2);
    unsigned short* act  = (unsigned short*)alloc((size_t)TTOK*2 * IDIM * 2);
    unsigned short* ybuf = (unsigned short*)alloc((size_t)TTOK*2 * HDIM * 2);

    hipMemsetAsync(cnt1, 0, NEXP*sizeof(int), stream);
    hipMemsetAsync(cnt2, 0, NEXP*sizeof(int), stream);

    router_kernel<<<dim3((TTOK+255)/256), 256, 0, stream>>>(logits, topi, topw, cnt1);
    scan_kernel<<<1, 64, 0, stream>>>(cnt1, base);
    assign_kernel<<<dim3((TTOK+255)/256), 256, 0, stream>>>(topi, base, cnt2, slot_token, slot_of);

    // GEMM1: h = x_gather @ w13^T   (NDIM=2816, KDIM=2048) — 44x4x16 blocks
    gemm_bt_kernel<2*IDIM, HDIM, true>
        <<<dim3(2*IDIM/64, CAP/128, NEXP), 256, 0, stream>>>(
            x, nullptr, w13, h, slot_token, base);

    silu_kernel<<<dim3((TTOK*2*(IDIM/8) + 255)/256), 256, 0, stream>>>(h, act, base);

    // GEMM2: y = act @ w2^T         (NDIM=2048, KDIM=1408) — 32x4x16 blocks
    gemm_bt_kernel<HDIM, IDIM, false>
        <<<dim3(HDIM/64, CAP/128, NEXP), 256, 0, stream>>>(
            nullptr, act, w2, ybuf, slot_token, base);

    combine_kernel<<<dim3(TTOK), 256, 0, stream>>>(ybuf, slot_of, topw, out);
}

// Round 3
// 730.885 us; speedup vs baseline: 1.0730x; 1.0378x over previous
//
#include <hip/hip_runtime.h>
#include <hip/hip_bf16.h>
#include <math.h>

#define NEXP 16
#define CAP  512
#define TTOK 1024
#define HDIM 2048
#define IDIM 1408
#define MAXR (TTOK*2)

typedef float fx4 __attribute__((ext_vector_type(4)));
typedef short short8 __attribute__((ext_vector_type(8)));
typedef unsigned int u32;
typedef unsigned long long u64;

__device__ __forceinline__ unsigned short f2bf(float f) {
    u32 u = __float_as_uint(f);
    u += 0x7FFFu + ((u >> 16) & 1u);       // round-to-nearest-even
    return (unsigned short)(u >> 16);
}
__device__ __forceinline__ float bf2f(unsigned short h) {
    return __uint_as_float(((u32)h) << 16);
}
__device__ __forceinline__ u64 pack4bf(fx4 f) {
    u32 lo = (u32)f2bf(f.x) | ((u32)f2bf(f.y) << 16);
    u32 hi = (u32)f2bf(f.z) | ((u32)f2bf(f.w) << 16);
    return (u64)lo | ((u64)hi << 32);
}

// ---------------- router
__global__ void router_kernel(const float* __restrict__ logits,
                              int* __restrict__ topi, float* __restrict__ topw,
                              int* __restrict__ cnt1) {
    int t = blockIdx.x * blockDim.x + threadIdx.x;
    if (t >= TTOK) return;
    const float* l = logits + t * NEXP;
    float b0 = -INFINITY, b1 = -INFINITY; int i0 = 0, i1 = 0;
    for (int e = 0; e < NEXP; ++e) {
        float v = l[e];
        if (v > b0) { b1 = b0; i1 = i0; b0 = v; i0 = e; }
        else if (v > b1) { b1 = v; i1 = e; }
    }
    float w0 = 1.f / (1.f + expf(b1 - b0));
    topi[t*2]   = i0; topi[t*2+1] = i1;
    topw[t*2]   = w0; topw[t*2+1] = 1.f - w0;
    atomicAdd(&cnt1[i0], 1);
    atomicAdd(&cnt1[i1], 1);
}

__global__ void scan_kernel(const int* __restrict__ cnt1, int* __restrict__ base) {
    if (threadIdx.x == 0 && blockIdx.x == 0) {
        int s = 0;
        for (int e = 0; e < NEXP; ++e) {
            base[e] = s;
            int c = cnt1[e]; if (c > CAP) c = CAP;
            s += c;
        }
        base[NEXP] = s;
    }
}

__global__ void assign_kernel(const int* __restrict__ topi, const int* __restrict__ base,
                              int* __restrict__ cnt2,
                              int* __restrict__ slot_token, int* __restrict__ slot_of) {
    int t = blockIdx.x * blockDim.x + threadIdx.x;
    if (t >= TTOK) return;
    for (int k = 0; k < 2; ++k) {
        int e = topi[t*2+k];
        int p = atomicAdd(&cnt2[e], 1);
        if (p < CAP) {
            int s = base[e] + p;
            slot_token[s] = t;
            slot_of[t*2+k] = s;
        } else {
            slot_of[t*2+k] = -1;
        }
    }
}

// ---------------- GEMM: Cpart[ks] = A @ W[e]^T over K-split ks, per expert.
// 128(rows) x 64(cols) tile, BK=32, split-K=SK (fp32 partial outputs).
// Depth-2 register prefetch + LDS double buffer: stage() waits loads issued a
// full iteration earlier; one barrier per iteration.
#define LDA 40

template<int NDIM, int KDIM, int SK, bool GATHER>
__global__ __launch_bounds__(256) void gemm_bt_kernel(
    const float* __restrict__ Af32,
    const unsigned short* __restrict__ Abf16,
    const float* __restrict__ W,
    float* __restrict__ Cpart,                 // [SK][MAXR][NDIM] fp32
    const int* __restrict__ slot_token,
    const int* __restrict__ base)
{
    const int e = blockIdx.z;
    const int n0 = base[e];
    const int rows = base[e+1] - n0;
    const int ks = blockIdx.y % SK;
    const int rtile = (blockIdx.y / SK) * 128;
    if (rtile >= rows) return;
    const int col0 = blockIdx.x * 64;
    const int kbase = ks * (KDIM / SK);

    __shared__ unsigned short sA[2][128 * LDA];
    __shared__ unsigned short sB[2][64 * LDA];

    const int tid = threadIdx.x;
    const int lane = tid & 63;
    const int wv = tid >> 6;
    const int lr = lane & 15;
    const int quad = lane >> 4;

    fx4 acc[2][4];
    #pragma unroll
    for (int i = 0; i < 2; ++i)
        #pragma unroll
        for (int j = 0; j < 4; ++j) acc[i][j] = (fx4)0.f;

    const int bg = tid & 7, bc = tid >> 3;
    const int ag = tid & 7, ar = tid >> 3;
    const int ag2 = tid & 3, ar2 = tid >> 2;

    int tok[4];
    if (GATHER) {
        #pragma unroll
        for (int p = 0; p < 4; ++p) {
            int grow = rtile + ar + p*32;
            tok[p] = (grow < rows) ? slot_token[n0 + grow] : -1;
        }
    } else {
        #pragma unroll
        for (int p = 0; p < 2; ++p) {
            int grow = rtile + ar2 + p*64;
            tok[p] = (grow < rows) ? (n0 + grow) : -1;
        }
    }

    const float* Wp = W + ((size_t)e * NDIM + col0) * KDIM + kbase;

    fx4 pa[2][4], pb[2][2];

    auto prefetch = [&](int slot, int k0) {
        #pragma unroll
        for (int p = 0; p < 2; ++p)
            pb[slot][p] = *(const fx4*)(Wp + (size_t)(bc + p*32) * KDIM + k0 + bg*4);
        if (GATHER) {
            #pragma unroll
            for (int p = 0; p < 4; ++p)
                pa[slot][p] = (tok[p] >= 0)
                    ? *(const fx4*)(Af32 + (size_t)tok[p]*KDIM + kbase + k0 + ag*4)
                    : (fx4)0.f;
        } else {
            #pragma unroll
            for (int p = 0; p < 2; ++p)
                pa[slot][p] = (tok[p] >= 0)
                    ? *(const fx4*)(Abf16 + (size_t)tok[p]*KDIM + kbase + k0 + ag2*8)
                    : (fx4)0.f;
        }
    };
    auto stage = [&](int buf, int slot) {
        #pragma unroll
        for (int p = 0; p < 2; ++p)
            *(u64*)&sB[buf][(bc + p*32)*LDA + bg*4] = pack4bf(pb[slot][p]);
        if (GATHER) {
            #pragma unroll
            for (int p = 0; p < 4; ++p)
                *(u64*)&sA[buf][(ar + p*32)*LDA + ag*4] = pack4bf(pa[slot][p]);
        } else {
            #pragma unroll
            for (int p = 0; p < 2; ++p)
                *(fx4*)&sA[buf][(ar2 + p*64)*LDA + ag2*8] = pa[slot][p];
        }
    };

    const int KT = (KDIM / SK) / 32;
    prefetch(0, 0);
    stage(0, 0);
    if (KT > 1) prefetch(1, 32);
    __syncthreads();

    for (int kt = 0; kt < KT; ++kt) {
        const int cur = kt & 1;
        if (kt + 2 < KT) prefetch(cur, (kt + 2) * 32);  // overwrites slot consumed last iter

        short8 af[2], bfr[4];
        #pragma unroll
        for (int mi = 0; mi < 2; ++mi)
            af[mi] = *(const short8*)&sA[cur][(wv*32 + mi*16 + lr)*LDA + quad*8];
        #pragma unroll
        for (int ni = 0; ni < 4; ++ni)
            bfr[ni] = *(const short8*)&sB[cur][(ni*16 + lr)*LDA + quad*8];
        #pragma unroll
        for (int mi = 0; mi < 2; ++mi)
            #pragma unroll
            for (int ni = 0; ni < 4; ++ni)
                acc[mi][ni] = __builtin_amdgcn_mfma_f32_16x16x32_bf16(
                    af[mi], bfr[ni], acc[mi][ni], 0, 0, 0);

        if (kt + 1 < KT) {
            stage(1 - cur, 1 - cur);   // waits loads issued one full iteration ago
            __syncthreads();
        }
    }

    // ---- epilogue: fp32 partial store. C/D layout col=lane&15, row=quad*4+reg
    float* Cp = Cpart + (size_t)ks * MAXR * NDIM;
    #pragma unroll
    for (int mi = 0; mi < 2; ++mi) {
        #pragma unroll
        for (int r = 0; r < 4; ++r) {
            int grow = rtile + wv*32 + mi*16 + quad*4 + r;
            if (grow < rows) {
                size_t orow = (size_t)(n0 + grow) * NDIM;
                #pragma unroll
                for (int ni = 0; ni < 4; ++ni) {
                    int gcol = col0 + ni*16 + lr;
                    Cp[orow + gcol] = acc[mi][ni][r];
                }
            }
        }
    }
}

// ---------------- silu(gate)*up over summed split-K partials (fp32 in, bf16 out)
__global__ void silu_kernel(const float* __restrict__ h,
                            unsigned short* __restrict__ act,
                            const int* __restrict__ base) {
    const int R = base[NEXP];
    int idx = blockIdx.x * blockDim.x + threadIdx.x;
    int row = idx / (IDIM/8);
    int j   = idx % (IDIM/8);
    if (row >= R) return;
    const float* g0 = h + (size_t)row * (2*IDIM) + j*8;
    const float* g1 = g0 + (size_t)MAXR * (2*IDIM);
    float gate[8], up[8];
    *(fx4*)&gate[0] = *(const fx4*)g0        + *(const fx4*)g1;
    *(fx4*)&gate[4] = *(const fx4*)(g0+4)    + *(const fx4*)(g1+4);
    *(fx4*)&up[0]   = *(const fx4*)(g0+IDIM)   + *(const fx4*)(g1+IDIM);
    *(fx4*)&up[4]   = *(const fx4*)(g0+IDIM+4) + *(const fx4*)(g1+IDIM+4);
    unsigned short ao[8];
    #pragma unroll
    for (int i = 0; i < 8; ++i) {
        float gv = gate[i];
        float s = gv / (1.f + __expf(-gv));
        ao[i] = f2bf(s * up[i]);
    }
    *(fx4*)&act[(size_t)row*IDIM + j*8] = *(fx4*)ao;
}

// ---------------- combine: out[t] = w0*(y0+y1)[s0] + w1*(y0+y1)[s1]
__global__ void combine_kernel(const float* __restrict__ ypart,
                               const int* __restrict__ slot_of,
                               const float* __restrict__ topw,
                               float* __restrict__ out) {
    int t = blockIdx.x;
    int c = threadIdx.x * 8;
    int s0 = slot_of[t*2], s1 = slot_of[t*2+1];
    float w0 = topw[t*2], w1 = topw[t*2+1];
    const float* y1b = ypart + (size_t)MAXR * HDIM;
    float res[8];
    #pragma unroll
    for (int i = 0; i < 8; ++i) res[i] = 0.f;
    if (s0 >= 0) {
        const float* p0 = ypart + (size_t)s0*HDIM + c;
        const float* p1 = y1b   + (size_t)s0*HDIM + c;
        #pragma unroll
        for (int i = 0; i < 8; ++i) res[i] += w0 * (p0[i] + p1[i]);
    }
    if (s1 >= 0) {
        const float* p0 = ypart + (size_t)s1*HDIM + c;
        const float* p1 = y1b   + (size_t)s1*HDIM + c;
        #pragma unroll
        for (int i = 0; i < 8; ++i) res[i] += w1 * (p0[i] + p1[i]);
    }
    float* o = out + (size_t)t*HDIM + c;
    *(fx4*)o       = *(fx4*)res;
    *(fx4*)(o + 4) = *(fx4*)(res + 4);
}

extern "C" void kernel_launch(void* const* d_in, const int* in_sizes, int n_in,
                              void* d_out, int out_size, void* d_ws, size_t ws_size,
                              hipStream_t stream) {
    const float* x      = (const float*)d_in[0];
    const float* logits = (const float*)d_in[1];
    const float* w13    = (const float*)d_in[2];
    const float* w2     = (const float*)d_in[3];
    float* out = (float*)d_out;

    char* ws = (char*)d_ws;
    size_t off = 0;
    auto alloc = [&](size_t bytes) -> void* {
        void* p = ws + off;
        off += (bytes + 255) & ~(size_t)255;
        return p;
    };
    int*   topi       = (int*)  alloc(TTOK*2*sizeof(int));
    float* topw       = (float*)alloc(TTOK*2*sizeof(float));
    int*   cnt1       = (int*)  alloc(NEXP*sizeof(int));
    int*   cnt2       = (int*)  alloc(NEXP*sizeof(int));
    int*   base       = (int*)  alloc((NEXP+1)*sizeof(int));
    int*   slot_token = (int*)  alloc(TTOK*2*sizeof(int));
    int*   slot_of    = (int*)  alloc(TTOK*2*sizeof(int));
    float* hpart = (float*)alloc((size_t)2 * MAXR * (2*IDIM) * sizeof(float));  // 46 MB
    unsigned short* act = (unsigned short*)alloc((size_t)MAXR * IDIM * 2);      // 5.8 MB
    float* ypart = (float*)alloc((size_t)2 * MAXR * HDIM * sizeof(float));      // 33.6 MB

    hipMemsetAsync(cnt1, 0, NEXP*sizeof(int), stream);
    hipMemsetAsync(cnt2, 0, NEXP*sizeof(int), stream);

    router_kernel<<<dim3((TTOK+255)/256), 256, 0, stream>>>(logits, topi, topw, cnt1);
    scan_kernel<<<1, 64, 0, stream>>>(cnt1, base);
    assign_kernel<<<dim3((TTOK+255)/256), 256, 0, stream>>>(topi, base, cnt2, slot_token, slot_of);

    // GEMM1: h = x_gather @ w13^T   (NDIM=2816, KDIM=2048, SK=2) -> 1408 active blocks
    gemm_bt_kernel<2*IDIM, HDIM, 2, true>
        <<<dim3(2*IDIM/64, (CAP/128)*2, NEXP), 256, 0, stream>>>(
            x, nullptr, w13, hpart, slot_token, base);

    silu_kernel<<<dim3((TTOK*2*(IDIM/8) + 255)/256), 256, 0, stream>>>(hpart, act, base);

    // GEMM2: y = act @ w2^T         (NDIM=2048, KDIM=1408, SK=2) -> 1024 active blocks
    gemm_bt_kernel<HDIM, IDIM, 2, false>
        <<<dim3(HDIM/64, (CAP/128)*2, NEXP), 256, 0, stream>>>(
            nullptr, act, w2, ypart, slot_token, base);

    combine_kernel<<<dim3(TTOK), 256, 0, stream>>>(ypart, slot_of, topw, out);
}

// Round 4
// 721.079 us; speedup vs baseline: 1.0876x; 1.0136x over previous
//
#include <hip/hip_runtime.h>
#include <hip/hip_bf16.h>
#include <math.h>

#define NEXP 16
#define CAP  512
#define TTOK 1024
#define HDIM 2048
#define IDIM 1408
#define MAXR (TTOK*2)

typedef float fx4 __attribute__((ext_vector_type(4)));
typedef short short8 __attribute__((ext_vector_type(8)));
typedef unsigned int u32;
typedef unsigned long long u64;

__device__ __forceinline__ unsigned short f2bf(float f) {
    u32 u = __float_as_uint(f);
    u += 0x7FFFu + ((u >> 16) & 1u);       // round-to-nearest-even
    return (unsigned short)(u >> 16);
}
__device__ __forceinline__ u64 pack4bf(fx4 f) {
    u32 lo = (u32)f2bf(f.x) | ((u32)f2bf(f.y) << 16);
    u32 hi = (u32)f2bf(f.z) | ((u32)f2bf(f.w) << 16);
    return (u64)lo | ((u64)hi << 32);
}

// ---------------- router
__global__ void router_kernel(const float* __restrict__ logits,
                              int* __restrict__ topi, float* __restrict__ topw,
                              int* __restrict__ cnt1) {
    int t = blockIdx.x * blockDim.x + threadIdx.x;
    if (t >= TTOK) return;
    const float* l = logits + t * NEXP;
    float b0 = -INFINITY, b1 = -INFINITY; int i0 = 0, i1 = 0;
    for (int e = 0; e < NEXP; ++e) {
        float v = l[e];
        if (v > b0) { b1 = b0; i1 = i0; b0 = v; i0 = e; }
        else if (v > b1) { b1 = v; i1 = e; }
    }
    float w0 = 1.f / (1.f + expf(b1 - b0));
    topi[t*2]   = i0; topi[t*2+1] = i1;
    topw[t*2]   = w0; topw[t*2+1] = 1.f - w0;
    atomicAdd(&cnt1[i0], 1);
    atomicAdd(&cnt1[i1], 1);
}

__global__ void scan_kernel(const int* __restrict__ cnt1, int* __restrict__ base) {
    if (threadIdx.x == 0 && blockIdx.x == 0) {
        int s = 0;
        for (int e = 0; e < NEXP; ++e) {
            base[e] = s;
            int c = cnt1[e]; if (c > CAP) c = CAP;
            s += c;
        }
        base[NEXP] = s;
    }
}

__global__ void assign_kernel(const int* __restrict__ topi, const int* __restrict__ base,
                              int* __restrict__ cnt2,
                              int* __restrict__ slot_token, int* __restrict__ slot_of) {
    int t = blockIdx.x * blockDim.x + threadIdx.x;
    if (t >= TTOK) return;
    for (int k = 0; k < 2; ++k) {
        int e = topi[t*2+k];
        int p = atomicAdd(&cnt2[e], 1);
        if (p < CAP) {
            int s = base[e] + p;
            slot_token[s] = t;
            slot_of[t*2+k] = s;
        } else {
            slot_of[t*2+k] = -1;
        }
    }
}

// ---------------- pre-gather: A1[s] = bf16(x[slot_token[s]]), compact rows
__global__ void gather_kernel(const float* __restrict__ x,
                              const int* __restrict__ slot_token,
                              const int* __restrict__ base,
                              unsigned short* __restrict__ A1) {
    int s = blockIdx.x;
    if (s >= base[NEXP]) return;
    int t = slot_token[s];
    int c = threadIdx.x * 8;            // 256 threads x 8 = 2048
    const float* src = x + (size_t)t * HDIM + c;
    fx4 a = *(const fx4*)src, b = *(const fx4*)(src + 4);
    u64 v[2] = { pack4bf(a), pack4bf(b) };
    *(fx4*)&A1[(size_t)s * HDIM + c] = *(fx4*)v;
}

// ---------------- GEMM: Cpart[ks] = A(bf16 compact) @ W[e]^T, per expert.
// 128(rows) x 64(cols) tile, BK=32, split-K=SK (fp32 partial outputs).
// Depth-2 register prefetch + LDS double buffer, one barrier per iteration.
#define LDA 40

template<int NDIM, int KDIM, int SK>
__global__ __launch_bounds__(256) void gemm_bt_kernel(
    const unsigned short* __restrict__ A,
    const float* __restrict__ W,
    float* __restrict__ Cpart,                 // [SK][MAXR][NDIM] fp32
    const int* __restrict__ base)
{
    const int e = blockIdx.z;
    const int n0 = base[e];
    const int rows = base[e+1] - n0;
    const int ks = blockIdx.y % SK;
    const int rtile = (blockIdx.y / SK) * 128;
    if (rtile >= rows) return;
    const int col0 = blockIdx.x * 64;
    const int kbase = ks * (KDIM / SK);

    __shared__ unsigned short sA[2][128 * LDA];
    __shared__ unsigned short sB[2][64 * LDA];

    const int tid = threadIdx.x;
    const int lane = tid & 63;
    const int wv = tid >> 6;
    const int lr = lane & 15;
    const int quad = lane >> 4;

    fx4 acc[2][4];
    #pragma unroll
    for (int i = 0; i < 2; ++i)
        #pragma unroll
        for (int j = 0; j < 4; ++j) acc[i][j] = (fx4)0.f;

    // A staging: 2 rows/thread, 16B (8 bf16) each
    const int ag = tid & 3, ar = tid >> 2;     // kseg 0..3, row 0..63
    // B staging: col 0..63, 2 fp32-quad segs/thread
    const int bg = tid & 3, bc = tid >> 2;

    int arow[2];
    #pragma unroll
    for (int p = 0; p < 2; ++p) {
        int grow = rtile + ar + p*64;
        arow[p] = (grow < rows) ? (n0 + grow) : -1;
    }

    const float* Wp = W + ((size_t)e * NDIM + col0) * KDIM + kbase;
    const unsigned short* Ap = A + kbase;

    fx4 pa[2][2], pb[2][2];

    auto prefetch = [&](int slot, int k0) {
        #pragma unroll
        for (int p = 0; p < 2; ++p)
            pb[slot][p] = *(const fx4*)(Wp + (size_t)bc * KDIM + k0 + (bg + p*4)*4);
        #pragma unroll
        for (int p = 0; p < 2; ++p)
            pa[slot][p] = (arow[p] >= 0)
                ? *(const fx4*)(Ap + (size_t)arow[p]*KDIM + k0 + ag*8)
                : (fx4)0.f;
    };
    auto stage = [&](int buf, int slot) {
        #pragma unroll
        for (int p = 0; p < 2; ++p)
            *(u64*)&sB[buf][bc*LDA + (bg + p*4)*4] = pack4bf(pb[slot][p]);
        #pragma unroll
        for (int p = 0; p < 2; ++p)
            *(fx4*)&sA[buf][(ar + p*64)*LDA + ag*8] = pa[slot][p];
    };

    const int KT = (KDIM / SK) / 32;
    prefetch(0, 0);
    stage(0, 0);
    if (KT > 1) prefetch(1, 32);
    __syncthreads();

    for (int kt = 0; kt < KT; ++kt) {
        const int cur = kt & 1;
        if (kt + 2 < KT) prefetch(cur, (kt + 2) * 32);

        short8 af[2], bfr[4];
        #pragma unroll
        for (int mi = 0; mi < 2; ++mi)
            af[mi] = *(const short8*)&sA[cur][(wv*32 + mi*16 + lr)*LDA + quad*8];
        #pragma unroll
        for (int ni = 0; ni < 4; ++ni)
            bfr[ni] = *(const short8*)&sB[cur][(ni*16 + lr)*LDA + quad*8];
        #pragma unroll
        for (int mi = 0; mi < 2; ++mi)
            #pragma unroll
            for (int ni = 0; ni < 4; ++ni)
                acc[mi][ni] = __builtin_amdgcn_mfma_f32_16x16x32_bf16(
                    af[mi], bfr[ni], acc[mi][ni], 0, 0, 0);

        if (kt + 1 < KT) {
            stage(1 - cur, 1 - cur);
            __syncthreads();
        }
    }

    // ---- epilogue: fp32 partial store. C/D layout col=lane&15, row=quad*4+reg
    float* Cp = Cpart + (size_t)ks * MAXR * NDIM;
    #pragma unroll
    for (int mi = 0; mi < 2; ++mi) {
        #pragma unroll
        for (int r = 0; r < 4; ++r) {
            int grow = rtile + wv*32 + mi*16 + quad*4 + r;
            if (grow < rows) {
                size_t orow = (size_t)(n0 + grow) * NDIM;
                #pragma unroll
                for (int ni = 0; ni < 4; ++ni) {
                    int gcol = col0 + ni*16 + lr;
                    Cp[orow + gcol] = acc[mi][ni][r];
                }
            }
        }
    }
}

// ---------------- silu(gate)*up over summed split-K partials (fp32 in, bf16 out)
__global__ void silu_kernel(const float* __restrict__ h,
                            unsigned short* __restrict__ act,
                            const int* __restrict__ base) {
    const int R = base[NEXP];
    int idx = blockIdx.x * blockDim.x + threadIdx.x;
    int row = idx / (IDIM/8);
    int j   = idx % (IDIM/8);
    if (row >= R) return;
    const float* g0 = h + (size_t)row * (2*IDIM) + j*8;
    const float* g1 = g0 + (size_t)MAXR * (2*IDIM);
    float gate[8], up[8];
    *(fx4*)&gate[0] = *(const fx4*)g0        + *(const fx4*)g1;
    *(fx4*)&gate[4] = *(const fx4*)(g0+4)    + *(const fx4*)(g1+4);
    *(fx4*)&up[0]   = *(const fx4*)(g0+IDIM)   + *(const fx4*)(g1+IDIM);
    *(fx4*)&up[4]   = *(const fx4*)(g0+IDIM+4) + *(const fx4*)(g1+IDIM+4);
    unsigned short ao[8];
    #pragma unroll
    for (int i = 0; i < 8; ++i) {
        float gv = gate[i];
        float s = gv / (1.f + __expf(-gv));
        ao[i] = f2bf(s * up[i]);
    }
    *(fx4*)&act[(size_t)row*IDIM + j*8] = *(fx4*)ao;
}

// ---------------- combine
__global__ void combine_kernel(const float* __restrict__ ypart,
                               const int* __restrict__ slot_of,
                               const float* __restrict__ topw,
                               float* __restrict__ out) {
    int t = blockIdx.x;
    int c = threadIdx.x * 8;
    int s0 = slot_of[t*2], s1 = slot_of[t*2+1];
    float w0 = topw[t*2], w1 = topw[t*2+1];
    const float* y1b = ypart + (size_t)MAXR * HDIM;
    float res[8];
    #pragma unroll
    for (int i = 0; i < 8; ++i) res[i] = 0.f;
    if (s0 >= 0) {
        const float* p0 = ypart + (size_t)s0*HDIM + c;
        const float* p1 = y1b   + (size_t)s0*HDIM + c;
        #pragma unroll
        for (int i = 0; i < 8; ++i) res[i] += w0 * (p0[i] + p1[i]);
    }
    if (s1 >= 0) {
        const float* p0 = ypart + (size_t)s1*HDIM + c;
        const float* p1 = y1b   + (size_t)s1*HDIM + c;
        #pragma unroll
        for (int i = 0; i < 8; ++i) res[i] += w1 * (p0[i] + p1[i]);
    }
    float* o = out + (size_t)t*HDIM + c;
    *(fx4*)o       = *(fx4*)res;
    *(fx4*)(o + 4) = *(fx4*)(res + 4);
}

extern "C" void kernel_launch(void* const* d_in, const int* in_sizes, int n_in,
                              void* d_out, int out_size, void* d_ws, size_t ws_size,
                              hipStream_t stream) {
    const float* x      = (const float*)d_in[0];
    const float* logits = (const float*)d_in[1];
    const float* w13    = (const float*)d_in[2];
    const float* w2     = (const float*)d_in[3];
    float* out = (float*)d_out;

    char* ws = (char*)d_ws;
    size_t off = 0;
    auto alloc = [&](size_t bytes) -> void* {
        void* p = ws + off;
        off += (bytes + 255) & ~(size_t)255;
        return p;
    };
    int*   topi       = (int*)  alloc(TTOK*2*sizeof(int));
    float* topw       = (float*)alloc(TTOK*2*sizeof(float));
    int*   cnt1       = (int*)  alloc(NEXP*sizeof(int));
    int*   cnt2       = (int*)  alloc(NEXP*sizeof(int));
    int*   base       = (int*)  alloc((NEXP+1)*sizeof(int));
    int*   slot_token = (int*)  alloc(TTOK*2*sizeof(int));
    int*   slot_of    = (int*)  alloc(TTOK*2*sizeof(int));
    unsigned short* A1  = (unsigned short*)alloc((size_t)MAXR * HDIM * 2);      // 8 MB
    float* hpart = (float*)alloc((size_t)2 * MAXR * (2*IDIM) * sizeof(float));  // 46 MB
    unsigned short* act = (unsigned short*)alloc((size_t)MAXR * IDIM * 2);      // 5.8 MB
    float* ypart = (float*)alloc((size_t)2 * MAXR * HDIM * sizeof(float));      // 33.6 MB

    hipMemsetAsync(cnt1, 0, NEXP*sizeof(int), stream);
    hipMemsetAsync(cnt2, 0, NEXP*sizeof(int), stream);

    router_kernel<<<dim3((TTOK+255)/256), 256, 0, stream>>>(logits, topi, topw, cnt1);
    scan_kernel<<<1, 64, 0, stream>>>(cnt1, base);
    assign_kernel<<<dim3((TTOK+255)/256), 256, 0, stream>>>(topi, base, cnt2, slot_token, slot_of);
    gather_kernel<<<dim3(MAXR), 256, 0, stream>>>(x, slot_token, base, A1);

    // GEMM1: h = A1 @ w13^T   (NDIM=2816, KDIM=2048, SK=2)
    gemm_bt_kernel<2*IDIM, HDIM, 2>
        <<<dim3(2*IDIM/64, (CAP/128)*2, NEXP), 256, 0, stream>>>(
            A1, w13, hpart, base);

    silu_kernel<<<dim3((TTOK*2*(IDIM/8) + 255)/256), 256, 0, stream>>>(hpart, act, base);

    // GEMM2: y = act @ w2^T   (NDIM=2048, KDIM=1408, SK=2)
    gemm_bt_kernel<HDIM, IDIM, 2>
        <<<dim3(HDIM/64, (CAP/128)*2, NEXP), 256, 0, stream>>>(
            act, w2, ypart, base);

    combine_kernel<<<dim3(TTOK), 256, 0, stream>>>(ypart, slot_of, topw, out);
}